// Round 6
// baseline (63.707 us; speedup 1.0000x reference)
//
#include <hip/hip_runtime.h>
#include <math.h>

// Problem constants
#define NB 4
#define BINS 256
#define HW (512*512)

// Pass-1 decomposition
#define CHUNKS 64                       // hist blocks per batch
#define PIX_PER_BLOCK (HW / CHUNKS)     // 4096
#define F4_PER_THREAD (PIX_PER_BLOCK / 4 / 256)  // 4
#define HIST_BLOCKS (NB * CHUNKS)       // 256

// Truncated correlation: |m-j| <= 64. Tail kernel mass ~1e-3 -> ~4e-5 abs
// output error vs 9.4e-4 threshold.
#define M_SUP 64
#define TAPS 130                        // 129 real taps + 1 zero pad (even count)
#define PAD_HI (TAPS - M_SUP)           // 66
#define HSP (M_SUP + BINS + PAD_HI)     // 386

#define DONE 0x600DF00Du                // != 0xAAAAAAAA poison

// ws layout: Hp[HIST_BLOCKS*BINS] uint | flag[HIST_BLOCKS] | part[NB] f32 | pflag[NB]

__global__ __launch_bounds__(256) void fused_entropy(const float* __restrict__ y,
                                                     unsigned* __restrict__ Hp,
                                                     unsigned* __restrict__ flag,
                                                     float* __restrict__ part,
                                                     unsigned* __restrict__ pflag,
                                                     float* __restrict__ out) {
    const int t = threadIdx.x;
    const int bid = blockIdx.x;

    if (bid < HIST_BLOCKS) {
        // ---- histogram role: per-(batch,chunk) hard histogram partial ----
        __shared__ unsigned lh[BINS];
        lh[t] = 0u;
        __syncthreads();

        const int b = bid >> 6;
        const int chunk = bid & 63;
        const float4* src = reinterpret_cast<const float4*>(
            y + (size_t)b * HW + (size_t)chunk * PIX_PER_BLOCK);
#pragma unroll
        for (int i = 0; i < F4_PER_THREAD; ++i) {
            float4 v = src[t + 256 * i];
            float vals[4] = {v.x, v.y, v.z, v.w};
#pragma unroll
            for (int c = 0; c < 4; ++c) {
                int bin = (int)(vals[c] * 256.0f);
                bin = bin < 0 ? 0 : (bin > 255 ? 255 : bin);
                atomicAdd(&lh[bin], 1u);            // ds_add_u32
            }
        }
        __syncthreads();
        Hp[(size_t)bid * BINS + t] = lh[t];          // coalesced 1 KB store
        __syncthreads();                             // drains vmcnt per wave -> stores in L2
        if (t == 0)                                  // publish (agent release: L2 writeback)
            __hip_atomic_store(&flag[bid], DONE,
                               __ATOMIC_RELEASE, __HIP_MEMORY_SCOPE_AGENT);
        return;
    }

    // ---- waiter role: one block per batch ----
    const int b = bid - HIST_BLOCKS;
    __shared__ float K0c[TAPS];
    __shared__ float Hs_pad[HSP];
    __shared__ float red[4];

    const float DELTA = 1.0f / 256.0f;
    const float SIGMA = 30.0f;

    // Build the truncated kernel table while the hist blocks run (hidden).
    if (t < TAPS) {
        float x = (float)(t - M_SUP) * DELTA;        // c_m - c_j
        float sp = 1.0f / (1.0f + __expf(-SIGMA * (x + 0.5f * DELTA)));
        float sm = 1.0f / (1.0f + __expf(-SIGMA * (x - 0.5f * DELTA)));
        K0c[t] = (t == TAPS - 1) ? 0.0f : (sp - sm);
    }
    if (t < M_SUP)  Hs_pad[t] = 0.0f;                // low pad
    if (t < PAD_HI) Hs_pad[M_SUP + BINS + t] = 0.0f; // high pad

    // Wait for this batch's 64 chunk partials (agent-acquire polls).
    if (t < CHUNKS) {
        const unsigned* f = &flag[b * CHUNKS + t];
        while (__hip_atomic_load(f, __ATOMIC_ACQUIRE,
                                 __HIP_MEMORY_SCOPE_AGENT) != DONE) {}
    }
    __syncthreads();                                 // all acquires ordered before reads

    // Reduce 64 chunk partials for bin t — coalesced (64 KB from L2/L3).
    unsigned H = 0u;
    const unsigned* hb = Hp + (size_t)b * CHUNKS * BINS + t;
#pragma unroll 8
    for (int c = 0; c < CHUNKS; ++c) H += hb[c * BINS];
    Hs_pad[M_SUP + t] = (float)H;
    __syncthreads();

    // Truncated 130-tap correlation for output bin j = t.
    // hist[j] = sum_{d=-64}^{65} K0c[d+64] * Hs_pad[64 + j + d]
    const int j = t;
    float hist = 0.0f;
#pragma unroll 10
    for (int i = 0; i < TAPS; i += 2) {
        hist = fmaf(K0c[i],     Hs_pad[j + i],     hist);
        hist = fmaf(K0c[i + 1], Hs_pad[j + i + 1], hist);
    }

    float p = hist * (1.0f / (float)HW) + 1e-6f;
    float e = -p * __logf(p);

    // Block-reduce the 256 entropy terms.
    const int lane = t & 63, wid = t >> 6;
#pragma unroll
    for (int off = 32; off > 0; off >>= 1) e += __shfl_down(e, off);
    if (lane == 0) red[wid] = e;
    __syncthreads();

    if (b != 0) {
        if (t == 0) {
            part[b] = red[0] + red[1] + red[2] + red[3];
            __hip_atomic_store(&pflag[b], DONE,
                               __ATOMIC_RELEASE, __HIP_MEMORY_SCOPE_AGENT);
        }
        return;
    }

    // Batch-0 block combines: wait for the other 3 partials.
    if (t >= 1 && t <= 3) {
        while (__hip_atomic_load(&pflag[t], __ATOMIC_ACQUIRE,
                                 __HIP_MEMORY_SCOPE_AGENT) != DONE) {}
    }
    __syncthreads();
    if (t == 0) {
        float d = red[0] + red[1] + red[2] + red[3]
                + part[1] + part[2] + part[3];
        out[0] = 1.0f / d;
    }
}

extern "C" void kernel_launch(void* const* d_in, const int* in_sizes, int n_in,
                              void* d_out, int out_size, void* d_ws, size_t ws_size,
                              hipStream_t stream) {
    const float* y = (const float*)d_in[0];
    unsigned* Hp = (unsigned*)d_ws;
    unsigned* flag = Hp + (size_t)HIST_BLOCKS * BINS;
    float* part = (float*)(flag + HIST_BLOCKS);
    unsigned* pflag = (unsigned*)(part + NB);

    fused_entropy<<<HIST_BLOCKS + NB, 256, 0, stream>>>(
        y, Hp, flag, part, pflag, (float*)d_out);
}